// Round 1
// baseline (766.684 us; speedup 1.0000x reference)
//
#include <hip/hip_runtime.h>

// LSTM T=2048,B=2048,H=32,I=1,O=1 fused in ONE kernel.
// R11: restructure 2-elem/wave -> 1-elem/wave with gate-split lane pairs.
// Diagnosis from R10 counters: Occupancy 11.4% = 1 wave/SIMD (1024 waves on
// 1024 SIMDs) -> nothing hides the h->gates->c->tanh->h chain; VALUBusy 64%
// = ~268 dyn VALU/step vs ~110 in source (AGPR shuffle from a 190-reg
// working set vs VGPR_Count=100). Fix both structurally:
//   lane 2j   owns rows i_j (gate A) and g_j (gate B)
//   lane 2j+1 owns rows f_j (gate A) and o_j (gate B)
// -> 2048 waves (2/SIMD, latency hiding), 2x16 pk-FMA dot work per lane
// (was 4x16), 64 weight VGPRs (was 128) so the whole working set (~130)
// fits the 256-VGPR budget at __launch_bounds__(256,2).
// Per step: one DPP quad_perm pair-swap moves iv*gv from even lane to its
// odd partner which owns c,h. Activation asymmetry is branchless via
// pre-scaled weights (-L2E sigmoid rows, +2*L2E tanh row) and per-lane
// affine gB = cB0 + cBm*rB. Even lanes compute bounded garbage c/h in
// lockstep (wout=0 there, so projection unaffected; no NaN possible).
// h published by odd lanes to LDS slots [0..31], junk to [32..63]
// (64 distinct slots = 2-way bank aliasing = free). Projection = full
// 64-lane DPP sum of h*wout, store from lane 63.

namespace {
constexpr int T_ = 2048;
constexpr int B_ = 2048;
constexpr int H_ = 32;
constexpr int WPB = 4;               // waves per block; 1 element per wave
constexpr int EPB = WPB;             // batch elements per block
constexpr int CHUNK = 64;            // timesteps of x held in one VGPR
constexpr int NCH = T_ / CHUNK;      // 32
constexpr int OUTS = T_ * B_;        // floats of outs [T,B,1]
constexpr float L2E = 1.442695040888963f;  // log2(e)

typedef float v2f __attribute__((ext_vector_type(2)));
typedef float v4f __attribute__((ext_vector_type(4)));

__device__ __forceinline__ float rcp_(float v){ return __builtin_amdgcn_rcpf(v); }
__device__ __forceinline__ float ex2_(float v){ return __builtin_amdgcn_exp2f(v); }

template <int CTRL, int RM, int BM, bool BC>
__device__ __forceinline__ float dpp_add(float acc, float src) {
    int mv = __builtin_amdgcn_update_dpp(0, __builtin_bit_cast(int, src),
                                         CTRL, RM, BM, BC);
    return acc + __builtin_bit_cast(float, mv);
}
// Full 64-lane sum; result valid in lane 63.
__device__ __forceinline__ float wave_sum64(float v) {
    v = dpp_add<0x111, 0xF, 0xF, true >(v, v);  // row_shr:1
    v = dpp_add<0x112, 0xF, 0xF, true >(v, v);  // row_shr:2
    v = dpp_add<0x114, 0xF, 0xF, true >(v, v);  // row_shr:4
    v = dpp_add<0x118, 0xF, 0xF, true >(v, v);  // row_shr:8
    v = dpp_add<0x142, 0xA, 0xF, false>(v, v);  // row_bcast:15 -> rows 1,3
    v = dpp_add<0x143, 0xC, 0xF, false>(v, v);  // row_bcast:31 -> rows 2,3
    return v;
}
// Swap within (even,odd) lane pairs: quad_perm [1,0,3,2].
__device__ __forceinline__ float pair_swap(float v) {
    int mv = __builtin_amdgcn_update_dpp(0, __builtin_bit_cast(int, v),
                                         0xB1, 0xF, 0xF, true);
    return __builtin_bit_cast(float, mv);
}
} // namespace

__global__ __launch_bounds__(256, 2)
void lstm_fused11(
    const float* __restrict__ x,      // [T,B,1]
    const float* __restrict__ W_ih,   // [4H,1]
    const float* __restrict__ W_hh,   // [4H,H]
    const float* __restrict__ b_ih,   // [4H]
    const float* __restrict__ b_hh,   // [4H]
    const float* __restrict__ W_out,  // [1,H]
    const float* __restrict__ b_out,  // [1]
    float* __restrict__ out)          // outs | hT | cT
{
    const int l   = threadIdx.x & 63;
    const int wv  = threadIdx.x >> 6;
    const int j   = l >> 1;            // hidden unit of this lane pair
    const int odd = l & 1;             // 0: (i,g) rows, 1: (f,o) rows
    const int e   = blockIdx.x * EPB + wv;

    __shared__ __align__(16) float hbuf[WPB][2 * H_];

    // Gate rows owned by this lane; weights pre-scaled so activations need
    // no dependent multiply before exp2.
    const float sclA = -L2E;                         // i / f are sigmoids
    const float sclB = odd ? -L2E : 2.0f * L2E;      // o sigmoid / g tanh
    const int rowA = odd ? (1*H_ + j) : j;           // f : i
    const int rowB = odd ? (3*H_ + j) : (2*H_ + j);  // o : g

    v2f wA[H_/2], wB[H_/2];
#pragma unroll
    for (int k2 = 0; k2 < H_/2; ++k2) {
        const float* rA = W_hh + rowA * H_;
        const float* rB = W_hh + rowB * H_;
        wA[k2] = (v2f){ rA[2*k2] * sclA, rA[2*k2+1] * sclA };
        wB[k2] = (v2f){ rB[2*k2] * sclB, rB[2*k2+1] * sclB };
    }
#pragma unroll
    for (int k2 = 0; k2 < H_/2; ++k2) {
        __asm__ __volatile__("" : "+v"(wA[k2]));
        __asm__ __volatile__("" : "+v"(wB[k2]));
    }

    const float wxA = W_ih[rowA] * sclA;
    const float wxB = W_ih[rowB] * sclB;
    const float bA  = (b_ih[rowA] + b_hh[rowA]) * sclA;
    const float bB  = (b_ih[rowB] + b_hh[rowB]) * sclB;
    // gB = cB0 + cBm * rcp(1+exp2(sB)):  even -> tanh(g), odd -> sigmoid(o)
    const float cB0 = odd ? 0.0f :  1.0f;
    const float cBm = odd ? 1.0f : -2.0f;
    const float wout = odd ? W_out[j] : 0.0f;  // even lanes contribute 0
    const float bout = b_out[0];
    const int   hslot = odd ? j : (H_ + j);    // real h at [0..31], junk above

    float c = 0.0f, h = 0.0f;
    v4f hq[H_/4];
#pragma unroll
    for (int q = 0; q < H_/4; ++q) hq[q] = (v4f){0.f, 0.f, 0.f, 0.f};  // h0=0

    float xcur = x[l * B_ + e];          // chunk 0: lane l holds t=l
    int outOff = e;                      // running offset: out[t*B_+e]

    for (int ch = 0; ch < NCH; ++ch) {
        float xnext = 0.0f;
        if (ch + 1 < NCH) xnext = x[((ch + 1) * CHUNK + l) * B_ + e];
#pragma unroll 8
        for (int s = 0; s < CHUNK; ++s) {
            // x broadcast: register readlane (h-independent, off the chain)
            const int xr = __builtin_amdgcn_readlane(__builtin_bit_cast(int, xcur), s);
            const float xk = __builtin_bit_cast(float, xr);
            const float xbA = bA + xk * wxA;    // off-chain, issues early
            const float xbB = bB + xk * wxB;
            // two dots of length 32 (2 chains each for ILP), first q peeled
            v2f aA0 = wA[0] * (v2f){hq[0].x, hq[0].y};
            v2f aA1 = wA[1] * (v2f){hq[0].z, hq[0].w};
            v2f aB0 = wB[0] * (v2f){hq[0].x, hq[0].y};
            v2f aB1 = wB[1] * (v2f){hq[0].z, hq[0].w};
#pragma unroll
            for (int q = 1; q < H_/4; ++q) {
                const v2f hlo = (v2f){hq[q].x, hq[q].y};
                const v2f hhi = (v2f){hq[q].z, hq[q].w};
                aA0 += wA[2*q]   * hlo;
                aA1 += wA[2*q+1] * hhi;
                aB0 += wB[2*q]   * hlo;
                aB1 += wB[2*q+1] * hhi;
            }
            const v2f aAv = aA0 + aA1;
            const v2f aBv = aB0 + aB1;
            const float sA = aAv.x + aAv.y + xbA;
            const float sB = aBv.x + aBv.y + xbB;
            const float actA = rcp_(1.0f + ex2_(sA));   // iv | fv
            const float rB   = rcp_(1.0f + ex2_(sB));
            const float gB   = cB0 + cBm * rB;          // gv | ov
            const float m    = actA * gB;               // iv*gv | (unused)
            const float mrecv = pair_swap(m);           // odd receives iv*gv
            c = actA * c + mrecv;                       // odd: fv*c + iv*gv
            const float tc = 1.0f - 2.0f * rcp_(1.0f + ex2_((2.0f * L2E) * c));
            h = gB * tc;                                // odd: ov*tanh(c)
            hbuf[wv][hslot] = h;                        // publish h_t
            __asm__ __volatile__("" ::: "memory");
            // issue NEXT step's h reads immediately; work below hides latency
#pragma unroll
            for (int q = 0; q < H_/4; ++q)
                hq[q] = ((const v4f*)&hbuf[wv][0])[q];
            // output projection: full-wave DPP sum (even lanes add 0)
            const float pr = wave_sum64(h * wout);
            if (l == 63) out[outOff] = pr + bout;
            outOff += B_;
        }
        xcur = xnext;
    }
    // Final states: hT [1,B,H] then cT [1,B,H] — real values on odd lanes.
    if (odd) {
        out[OUTS + e * H_ + j] = h;
        out[OUTS + B_ * H_ + e * H_ + j] = c;
    }
}

extern "C" void kernel_launch(void* const* d_in, const int* in_sizes, int n_in,
                              void* d_out, int out_size, void* d_ws, size_t ws_size,
                              hipStream_t stream) {
    const float* x     = (const float*)d_in[0];
    const float* W_ih  = (const float*)d_in[1];
    const float* W_hh  = (const float*)d_in[2];
    const float* b_ih  = (const float*)d_in[3];
    const float* b_hh  = (const float*)d_in[4];
    const float* W_out = (const float*)d_in[5];
    const float* b_out = (const float*)d_in[6];
    lstm_fused11<<<dim3(B_ / EPB), dim3(256), 0, stream>>>(
        x, W_ih, W_hh, b_ih, b_hh, W_out, b_out, (float*)d_out);
}

// Round 2
// 722.724 us; speedup vs baseline: 1.0608x; 1.0608x over previous
//
#include <hip/hip_runtime.h>

// LSTM T=2048,B=2048,H=32,I=1,O=1 fused in ONE kernel.
// R12 = R11 structure (1 elem/wave, gate-split lane pairs, 2 waves/SIMD)
// with the register working set HALVED via f16 packing + v_dot2_f32_f16
// (f32 accumulate; only W_hh and h are f16 -- biases/x/state stay f32).
// Diagnosis: R10/R11 are VALU-issue-bound with dynamic-instruction
// inflation that tracks (declared_regs - VGPR_Count): ~90 parked values in
// R10 (190 vs 100), ~50 in R11 (110 vs 64). Allocator cap never moves with
// attributes, so shrink demand under it: weights 64->32 dwords, h fragment
// 32->16 dwords, total ~72 dwords. Also halves the LDS h reload to 4x
// ds_read_b128. Everything else (proven R11 dataflow) unchanged:
//   lane 2j:   rows i_j (A) and g_j (B);  lane 2j+1: rows f_j (A), o_j (B)
//   DPP quad_perm pair-swap moves iv*gv to the odd lane owning c,h.
//   Even lanes compute bounded junk c/h (wout=0, rcp(inf)=0 -> no NaN).

namespace {
constexpr int T_ = 2048;
constexpr int B_ = 2048;
constexpr int H_ = 32;
constexpr int WPB = 4;               // waves per block; 1 element per wave
constexpr int EPB = WPB;             // batch elements per block
constexpr int CHUNK = 64;            // timesteps of x held in one VGPR
constexpr int NCH = T_ / CHUNK;      // 32
constexpr int OUTS = T_ * B_;        // floats of outs [T,B,1]
constexpr float L2E = 1.442695040888963f;  // log2(e)

typedef _Float16 v2h __attribute__((ext_vector_type(2)));
typedef unsigned int u32;
typedef u32 v4u __attribute__((ext_vector_type(4)));

__device__ __forceinline__ float rcp_(float v){ return __builtin_amdgcn_rcpf(v); }
__device__ __forceinline__ float ex2_(float v){ return __builtin_amdgcn_exp2f(v); }

// 2-MAC f16 dot with f32 accumulator (v_dot2_f32_f16).
__device__ __forceinline__ float fdot2_(v2h a, v2h b, float c) {
#if __has_builtin(__builtin_amdgcn_fdot2)
    return __builtin_amdgcn_fdot2(a, b, c, false);
#else
    return c + (float)a.x * (float)b.x + (float)a.y * (float)b.y;
#endif
}

template <int CTRL, int RM, int BM, bool BC>
__device__ __forceinline__ float dpp_add(float acc, float src) {
    int mv = __builtin_amdgcn_update_dpp(0, __builtin_bit_cast(int, src),
                                         CTRL, RM, BM, BC);
    return acc + __builtin_bit_cast(float, mv);
}
// Full 64-lane sum; result valid in lane 63.
__device__ __forceinline__ float wave_sum64(float v) {
    v = dpp_add<0x111, 0xF, 0xF, true >(v, v);  // row_shr:1
    v = dpp_add<0x112, 0xF, 0xF, true >(v, v);  // row_shr:2
    v = dpp_add<0x114, 0xF, 0xF, true >(v, v);  // row_shr:4
    v = dpp_add<0x118, 0xF, 0xF, true >(v, v);  // row_shr:8
    v = dpp_add<0x142, 0xA, 0xF, false>(v, v);  // row_bcast:15 -> rows 1,3
    v = dpp_add<0x143, 0xC, 0xF, false>(v, v);  // row_bcast:31 -> rows 2,3
    return v;
}
// Swap within (even,odd) lane pairs: quad_perm [1,0,3,2].
__device__ __forceinline__ float pair_swap(float v) {
    int mv = __builtin_amdgcn_update_dpp(0, __builtin_bit_cast(int, v),
                                         0xB1, 0xF, 0xF, true);
    return __builtin_bit_cast(float, mv);
}
} // namespace

__global__ __launch_bounds__(256, 2)
void lstm_fused12(
    const float* __restrict__ x,      // [T,B,1]
    const float* __restrict__ W_ih,   // [4H,1]
    const float* __restrict__ W_hh,   // [4H,H]
    const float* __restrict__ b_ih,   // [4H]
    const float* __restrict__ b_hh,   // [4H]
    const float* __restrict__ W_out,  // [1,H]
    const float* __restrict__ b_out,  // [1]
    float* __restrict__ out)          // outs | hT | cT
{
    const int l   = threadIdx.x & 63;
    const int wv  = threadIdx.x >> 6;
    const int j   = l >> 1;            // hidden unit of this lane pair
    const int odd = l & 1;             // 0: (i,g) rows, 1: (f,o) rows
    const int e   = blockIdx.x * EPB + wv;

    // h published as f16: real h at [0..31], junk at [32..63].
    __shared__ __align__(16) _Float16 hbuf[WPB][2 * H_];

    const float sclA = -L2E;                         // i / f are sigmoids
    const float sclB = odd ? -L2E : 2.0f * L2E;      // o sigmoid / g tanh
    const int rowA = odd ? (1*H_ + j) : j;           // f : i
    const int rowB = odd ? (3*H_ + j) : (2*H_ + j);  // o : g

    // Pre-scaled f16 weight pairs: 16+16 dwords.
    v2h wA[H_/2], wB[H_/2];
#pragma unroll
    for (int k2 = 0; k2 < H_/2; ++k2) {
        const float* rA = W_hh + rowA * H_;
        const float* rB = W_hh + rowB * H_;
        wA[k2] = (v2h){ (_Float16)(rA[2*k2] * sclA), (_Float16)(rA[2*k2+1] * sclA) };
        wB[k2] = (v2h){ (_Float16)(rB[2*k2] * sclB), (_Float16)(rB[2*k2+1] * sclB) };
    }
#pragma unroll
    for (int k2 = 0; k2 < H_/2; ++k2) {
        __asm__ __volatile__("" : "+v"(wA[k2]));
        __asm__ __volatile__("" : "+v"(wB[k2]));
    }

    const float wxA = W_ih[rowA] * sclA;
    const float wxB = W_ih[rowB] * sclB;
    const float bA  = (b_ih[rowA] + b_hh[rowA]) * sclA;
    const float bB  = (b_ih[rowB] + b_hh[rowB]) * sclB;
    // gB = cB0 + cBm * rcp(1+exp2(sB)):  even -> tanh(g), odd -> sigmoid(o)
    const float cB0 = odd ? 0.0f :  1.0f;
    const float cBm = odd ? 1.0f : -2.0f;
    const float wout = odd ? W_out[j] : 0.0f;  // even lanes contribute 0
    const float bout = b_out[0];
    const int   hslot = odd ? j : (H_ + j);    // real h at [0..31]

    float c = 0.0f, h = 0.0f;
    // h fragment: 32 f16 = 16 dwords, each dword = one (h_{2k},h_{2k+1}) pair.
    u32 hq[H_/2];
#pragma unroll
    for (int k2 = 0; k2 < H_/2; ++k2) hq[k2] = 0u;   // h0 = 0 (f16 zeros)

    float xcur = x[l * B_ + e];          // chunk 0: lane l holds t=l
    int outOff = e;                      // running offset: out[t*B_+e]

    for (int ch = 0; ch < NCH; ++ch) {
        float xnext = 0.0f;
        if (ch + 1 < NCH) xnext = x[((ch + 1) * CHUNK + l) * B_ + e];
#pragma unroll 8
        for (int s = 0; s < CHUNK; ++s) {
            // x broadcast: register readlane (h-independent, off the chain)
            const int xr = __builtin_amdgcn_readlane(__builtin_bit_cast(int, xcur), s);
            const float xk = __builtin_bit_cast(float, xr);
            // dot accumulators start at the x-term (saves the merge adds)
            float aA0 = bA + xk * wxA, aA1 = 0.f;
            float aB0 = bB + xk * wxB, aB1 = 0.f;
#pragma unroll
            for (int k2 = 0; k2 < H_/2; k2 += 2) {
                const v2h h0 = __builtin_bit_cast(v2h, hq[k2]);
                const v2h h1 = __builtin_bit_cast(v2h, hq[k2+1]);
                aA0 = fdot2_(wA[k2],   h0, aA0);
                aA1 = fdot2_(wA[k2+1], h1, aA1);
                aB0 = fdot2_(wB[k2],   h0, aB0);
                aB1 = fdot2_(wB[k2+1], h1, aB1);
            }
            const float sA = aA0 + aA1;
            const float sB = aB0 + aB1;
            const float actA = rcp_(1.0f + ex2_(sA));   // iv | fv
            const float rB   = rcp_(1.0f + ex2_(sB));
            const float gB   = cB0 + cBm * rB;          // gv | ov
            const float m    = actA * gB;               // iv*gv | (unused)
            const float mrecv = pair_swap(m);           // odd receives iv*gv
            c = actA * c + mrecv;                       // odd: fv*c + iv*gv
            const float tc = 1.0f - 2.0f * rcp_(1.0f + ex2_((2.0f * L2E) * c));
            h = gB * tc;                                // odd: ov*tanh(c)
            hbuf[wv][hslot] = (_Float16)h;              // publish h_t (f16)
            __asm__ __volatile__("" ::: "memory");
            // issue NEXT step's h reads immediately; work below hides latency
            {
                const v4u* hp = (const v4u*)&hbuf[wv][0];
#pragma unroll
                for (int q = 0; q < 4; ++q) {
                    const v4u v = hp[q];               // ds_read_b128
                    hq[4*q+0] = v.x; hq[4*q+1] = v.y;
                    hq[4*q+2] = v.z; hq[4*q+3] = v.w;
                }
            }
            // output projection: full-wave DPP sum (even lanes add 0)
            const float pr = wave_sum64(h * wout);
            if (l == 63) out[outOff] = pr + bout;
            outOff += B_;
        }
        xcur = xnext;
    }
    // Final states: hT [1,B,H] then cT [1,B,H] — real values on odd lanes.
    if (odd) {
        out[OUTS + e * H_ + j] = h;
        out[OUTS + B_ * H_ + e * H_ + j] = c;
    }
}

extern "C" void kernel_launch(void* const* d_in, const int* in_sizes, int n_in,
                              void* d_out, int out_size, void* d_ws, size_t ws_size,
                              hipStream_t stream) {
    const float* x     = (const float*)d_in[0];
    const float* W_ih  = (const float*)d_in[1];
    const float* W_hh  = (const float*)d_in[2];
    const float* b_ih  = (const float*)d_in[3];
    const float* b_hh  = (const float*)d_in[4];
    const float* W_out = (const float*)d_in[5];
    const float* b_out = (const float*)d_in[6];
    lstm_fused12<<<dim3(B_ / EPB), dim3(256), 0, stream>>>(
        x, W_ih, W_hh, b_ih, b_hh, W_out, b_out, (float*)d_out);
}

// Round 8
// 719.958 us; speedup vs baseline: 1.0649x; 1.0038x over previous
//
#include <hip/hip_runtime.h>

// LSTM T=2048,B=2048,H=32,I=1,O=1 fused in ONE kernel.
// R18 = round-0's PASSING kernel (lstm_fused10, 715us, absmax 9.766e-4,
// f32 recurrence, 2 elem/wave) with exactly TWO deletions:
//   (1) ALL asm "+v" init-time pins removed (untested pin theory: pinning
//       128 weight dwords against a 100-VGPR grant forces all other values
//       through ~8 free regs -> per-step copy engine).
//   (2) amdgpu_num_vgpr(256) removed (measured no-op in round 0).
// WHY RETREAT FROM f16: R15/R16/R17 all failed with the BIT-IDENTICAL
// error 1.660156e-2 across three different projection datapaths; the only
// shared bit-exact component is the f16 recurrent h trajectory. R17 was
// bit-identical math to the once-passing R12 and still failed -> the f16
// recurrence's true error (~1.6e-2 after 2048 steps vs a high-precision
// np reference) exceeds the 1.008e-2 threshold. f32 recurrence passed with
// 10x margin under both measurement regimes. f16 recurrence abandoned.
// absmax prediction: EXACTLY 0.0009765625 (bit-identical to round 0) --
// canary that this binary ran; 1.66e-2 would mean stale harness.
// Shape (R7/R10): wave64 = 2 batch elements in lockstep halves; lane owns
// unit j=l&31 of its half's element, computes all 4 gates; f32 throughout;
// LDS h broadcast; DPP O=1 projection; v_readlane x broadcast.

namespace {
constexpr int T_ = 2048;
constexpr int B_ = 2048;
constexpr int H_ = 32;
constexpr int WPB = 4;              // waves per block; each wave = 2 elements
constexpr int EPB = WPB * 2;        // batch elements per block
constexpr int CHUNK = 32;           // timesteps of x held in one VGPR
constexpr int NCH = T_ / CHUNK;     // 64
constexpr int OUTS = T_ * B_;       // floats of outs [T,B,1]
constexpr float L2E = 1.442695040888963f;  // log2(e)

typedef float v2f __attribute__((ext_vector_type(2)));
typedef float v4f __attribute__((ext_vector_type(4)));

__device__ __forceinline__ float rcp_(float v){ return __builtin_amdgcn_rcpf(v); }
__device__ __forceinline__ float ex2_(float v){ return __builtin_amdgcn_exp2f(v); }

template <int CTRL, int RM, int BM, bool BC>
__device__ __forceinline__ float dpp_add(float acc, float src) {
    int mv = __builtin_amdgcn_update_dpp(0, __builtin_bit_cast(int, src),
                                         CTRL, RM, BM, BC);
    return acc + __builtin_bit_cast(float, mv);
}
// Sum within each 32-lane half; result in lane 31 (half0) / lane 63 (half1).
__device__ __forceinline__ float half_sum32(float v) {
    v = dpp_add<0x111, 0xF, 0xF, true >(v, v);  // row_shr:1
    v = dpp_add<0x112, 0xF, 0xF, true >(v, v);  // row_shr:2
    v = dpp_add<0x114, 0xF, 0xF, true >(v, v);  // row_shr:4
    v = dpp_add<0x118, 0xF, 0xF, true >(v, v);  // row_shr:8
    v = dpp_add<0x142, 0xA, 0xF, false>(v, v);  // row_bcast:15 -> rows 1,3
    return v;
}
} // namespace

__global__ __launch_bounds__(256, 1)
void lstm_fused18(
    const float* __restrict__ x,      // [T,B,1]
    const float* __restrict__ W_ih,   // [4H,1]
    const float* __restrict__ W_hh,   // [4H,H]
    const float* __restrict__ b_ih,   // [4H]
    const float* __restrict__ b_hh,   // [4H]
    const float* __restrict__ W_out,  // [1,H]
    const float* __restrict__ b_out,  // [1]
    float* __restrict__ out)          // outs | hT | cT
{
    const int l  = threadIdx.x & 63;
    const int wv = threadIdx.x >> 6;
    const int j  = l & 31;            // hidden unit
    const int p  = l >> 5;            // element half within wave
    const int e  = blockIdx.x * EPB + wv * 2 + p;

    __shared__ __align__(16) float hbuf[WPB][2][H_];

    const float sI = -L2E, sF = -L2E, sG = 2.0f * L2E, sO = -L2E;

    // W_hh rows j (i), j+H (f), j+2H (g), j+3H (o); packed k-pairs, pre-scaled
    // so activations need no dependent mul before exp2. NO PINS.
    v2f wi[H_/2], wf[H_/2], wg[H_/2], wo[H_/2];
#pragma unroll
    for (int k2 = 0; k2 < H_/2; ++k2) {
        const float* ri = W_hh + (0*H_ + j) * H_;
        const float* rf = W_hh + (1*H_ + j) * H_;
        const float* rg = W_hh + (2*H_ + j) * H_;
        const float* ro = W_hh + (3*H_ + j) * H_;
        wi[k2] = (v2f){ ri[2*k2] * sI, ri[2*k2+1] * sI };
        wf[k2] = (v2f){ rf[2*k2] * sF, rf[2*k2+1] * sF };
        wg[k2] = (v2f){ rg[2*k2] * sG, rg[2*k2+1] * sG };
        wo[k2] = (v2f){ ro[2*k2] * sO, ro[2*k2+1] * sO };
    }

    const float wxi = W_ih[0*H_+j] * sI, wxf = W_ih[1*H_+j] * sF;
    const float wxg = W_ih[2*H_+j] * sG, wxo = W_ih[3*H_+j] * sO;
    const float bi  = (b_ih[0*H_+j] + b_hh[0*H_+j]) * sI;
    const float bf  = (b_ih[1*H_+j] + b_hh[1*H_+j]) * sF;
    const float bg  = (b_ih[2*H_+j] + b_hh[2*H_+j]) * sG;
    const float bo_ = (b_ih[3*H_+j] + b_hh[3*H_+j]) * sO;
    const float wout = W_out[j];
    const float bout = b_out[0];

    float c = 0.0f, h = 0.0f;
    hbuf[wv][p][j] = 0.0f;               // h0 = 0
    __asm__ __volatile__("" ::: "memory");
    v4f hq[H_/4];
#pragma unroll
    for (int q = 0; q < H_/4; ++q)       // h_0 fragments for step 0
        hq[q] = ((const v4f*)&hbuf[wv][p][0])[q];

    float xcur = x[j * B_ + e];          // chunk 0: lane j holds t=j
    int outOff = e;                      // running offset: out[t*B_+e]

    for (int ch = 0; ch < NCH; ++ch) {
        float xnext = 0.0f;
        if (ch + 1 < NCH) xnext = x[((ch + 1) * CHUNK + j) * B_ + e];
#pragma unroll 8
        for (int s = 0; s < CHUNK; ++s) {
            // x broadcast: register readlane (h-independent, off the chain)
            const int xr0 = __builtin_amdgcn_readlane(__builtin_bit_cast(int, xcur), s);
            const int xr1 = __builtin_amdgcn_readlane(__builtin_bit_cast(int, xcur), s + 32);
            const float xk = p ? __builtin_bit_cast(float, xr1)
                               : __builtin_bit_cast(float, xr0);
            // dot accumulators start at the x-term (saves the merge adds)
            v2f ai0 = {bi  + xk * wxi, 0.f}, ai1 = {0.f, 0.f};
            v2f af0 = {bf  + xk * wxf, 0.f}, af1 = {0.f, 0.f};
            v2f ag0 = {bg  + xk * wxg, 0.f}, ag1 = {0.f, 0.f};
            v2f ao0 = {bo_ + xk * wxo, 0.f}, ao1 = {0.f, 0.f};
#pragma unroll
            for (int q = 0; q < H_/4; ++q) {
                const v2f hlo = (v2f){ hq[q].x, hq[q].y };
                const v2f hhi = (v2f){ hq[q].z, hq[q].w };
                ai0 += wi[2*q] * hlo;  ai1 += wi[2*q+1] * hhi;
                af0 += wf[2*q] * hlo;  af1 += wf[2*q+1] * hhi;
                ag0 += wg[2*q] * hlo;  ag1 += wg[2*q+1] * hhi;
                ao0 += wo[2*q] * hlo;  ao1 += wo[2*q+1] * hhi;
            }
            const v2f ai = ai0 + ai1, af = af0 + af1;
            const v2f ag = ag0 + ag1, ao = ao0 + ao1;
            const float iv = rcp_(1.0f + ex2_(ai.x + ai.y));
            const float fv = rcp_(1.0f + ex2_(af.x + af.y));
            const float gv = 1.0f - 2.0f * rcp_(1.0f + ex2_(ag.x + ag.y));
            const float ov = rcp_(1.0f + ex2_(ao.x + ao.y));
            c = fv * c + iv * gv;
            const float tc = 1.0f - 2.0f * rcp_(1.0f + ex2_((2.0f * L2E) * c));
            h = ov * tc;
            hbuf[wv][p][j] = h;           // publish h_t
            __asm__ __volatile__("" ::: "memory");
            // issue NEXT step's h reads immediately; work below hides latency
#pragma unroll
            for (int q = 0; q < H_/4; ++q)
                hq[q] = ((const v4f*)&hbuf[wv][p][0])[q];
            // output projection: DPP half-sum (pure VALU, no lgkm waits)
            const float pr = half_sum32(h * wout);
            if ((l & 31) == 31) out[outOff] = pr + bout;
            outOff += B_;
        }
        xcur = xnext;
    }
    // Final states: hT [1,B,H] then cT [1,B,H] — valid on every lane.
    out[OUTS + e * H_ + j] = h;
    out[OUTS + B_ * H_ + e * H_ + j] = c;
}

extern "C" void kernel_launch(void* const* d_in, const int* in_sizes, int n_in,
                              void* d_out, int out_size, void* d_ws, size_t ws_size,
                              hipStream_t stream) {
    const float* x     = (const float*)d_in[0];
    const float* W_ih  = (const float*)d_in[1];
    const float* W_hh  = (const float*)d_in[2];
    const float* b_ih  = (const float*)d_in[3];
    const float* b_hh  = (const float*)d_in[4];
    const float* W_out = (const float*)d_in[5];
    const float* b_out = (const float*)d_in[6];
    lstm_fused18<<<dim3(B_ / EPB), dim3(256), 0, stream>>>(
        x, W_ih, W_hh, b_ih, b_hh, W_out, b_out, (float*)d_out);
}